// Round 7
// baseline (428.577 us; speedup 1.0000x reference)
//
#include <hip/hip_runtime.h>
#include <hip/hip_bf16.h>

typedef __attribute__((ext_vector_type(8))) short bf16x8;
typedef __attribute__((ext_vector_type(4))) float f32x4;
typedef unsigned short u16;
typedef unsigned int u32;

__device__ __forceinline__ u32 bf16_rne(float f) {
  u32 u = __float_as_uint(f);
  return (u + 0x7FFFu + ((u >> 16) & 1u)) >> 16;
}
__device__ __forceinline__ float bf16_val(u32 b) { return __uint_as_float(b << 16); }

__device__ __forceinline__ void g2l16(const u16* g, u16* l) {
  __builtin_amdgcn_global_load_lds(
      (const __attribute__((address_space(1))) u32*)g,
      (__attribute__((address_space(3))) u32*)l, 16, 0, 0);
}

// ---- split fp32 -> interleaved [blk][2][chunkElems] bf16 hi/lo ----
__global__ void split_pairs(const float* __restrict__ in, u16* __restrict__ out,
                            int n4, int chunk4) {
  int i = blockIdx.x * 256 + threadIdx.x;
  if (i >= n4) return;
  float4 v = ((const float4*)in)[i];
  u32 h0 = bf16_rne(v.x), h1 = bf16_rne(v.y), h2 = bf16_rne(v.z), h3 = bf16_rne(v.w);
  u32 l0 = bf16_rne(v.x - bf16_val(h0));
  u32 l1 = bf16_rne(v.y - bf16_val(h1));
  u32 l2 = bf16_rne(v.z - bf16_val(h2));
  u32 l3 = bf16_rne(v.w - bf16_val(h3));
  ushort4 hv; hv.x = (u16)h0; hv.y = (u16)h1; hv.z = (u16)h2; hv.w = (u16)h3;
  ushort4 lv; lv.x = (u16)l0; lv.y = (u16)l1; lv.z = (u16)l2; lv.w = (u16)l3;
  int blk = i / chunk4, off = i % chunk4;
  ((ushort4*)out)[(size_t)blk * 2 * chunk4 + off] = hv;
  ((ushort4*)out)[(size_t)blk * 2 * chunk4 + chunk4 + off] = lv;
}

// ---- transpose each 256x256 fp32 slice, split into interleaved hi/lo ----
// out layout: [z][2][256][256]
__global__ void split_transpose256(const float* __restrict__ in, u16* __restrict__ out) {
  __shared__ float tile[32][33];
  const size_t zin = (size_t)blockIdx.z * 65536;
  const size_t zout = (size_t)blockIdx.z * 131072;
  const int tx = threadIdx.x, ty = threadIdx.y;
#pragma unroll
  for (int i = 0; i < 4; ++i) {
    int y = blockIdx.y * 32 + ty + i * 8;
    int x = blockIdx.x * 32 + tx;
    tile[ty + i * 8][tx] = in[zin + (size_t)y * 256 + x];
  }
  __syncthreads();
#pragma unroll
  for (int i = 0; i < 4; ++i) {
    float v = tile[tx][ty + i * 8];
    u32 hb = bf16_rne(v);
    u32 lb = bf16_rne(v - bf16_val(hb));
    size_t idx = (size_t)(blockIdx.x * 32 + ty + i * 8) * 256 + blockIdx.y * 32 + tx;
    out[zout + idx] = (u16)hb;
    out[zout + 65536 + idx] = (u16)lb;
  }
}

// ---------------- fused priors-GEMM (split-bf16) + dynamic routing ----------------
// 512 threads = 8 waves. FULL-COLUMN wave split: wave w owns ALL R rows x cols
// [w*32, w*32+32). P[b,e]: b = mt*16 + q*4 + r, e = w*32 + ct*16 + li.
// A (R x 256 hi/lo) is k-resident in LDS: staged once per pass (stage1: 2 passes
// of 128 k-cols; stage2: 1 pass of 256). B is wave-private: 16B/lane global
// loads into registers, software-pipelined, no barrier.
// LDS chunk = 16 rows x 32k x 2B = 1024 B; DMA lane i holds (row=i&15, qslab=i>>4)
// so fragment reads are chunkbase + lane*16 (stride-1, conflict-free).
template <int R>
__global__ __launch_bounds__(512, 4) void caps_route(
    const u16* __restrict__ Ain,     // [64][2][R][256] interleaved hi/lo
    const u16* __restrict__ Win,     // [KN][2][256][256] interleaved hi/lo ([e][d])
    u16* __restrict__ o1,            // stage1 out: [64][2][KN][256]
    float* __restrict__ outp,        // stage2 out
    int KN, int stage) {
  constexpr int MT = R / 16;                 // 8 (stage1) or 4 (stage2)
  constexpr int PASSES = (R == 128) ? 2 : 1;
  constexpr int KS = 8 / PASSES;             // ksteps per pass (4 or 8)
  // resident A chunks per pass: KS * 2(part) * MT = 64 either way
  __shared__ __align__(16) u16 ABUF[64 * 512];   // 64 KB
  __shared__ __align__(16) float wlog[8][R];
  __shared__ float logits[R];
  __shared__ __align__(16) float probs[R];
  __shared__ float sqpart[8];

  const int tid = threadIdx.x;
  const int w = tid >> 6, lane = tid & 63, q = lane >> 4, li = lane & 15;
  const int kk = blockIdx.x >> 6;   // weight slice (h or c)
  const int a  = blockIdx.x & 63;

  const u16* Aab = Ain + (size_t)a * 2 * R * 256;
  const u16* Wkk = Win + (size_t)kk * 131072;
  // per-lane B base: e-row = w*32 + li (ct adds 16 rows = 4096 elems; lo part += 65536)
  const u16* Bp = Wkk + (size_t)(w * 32 + li) * 256 + q * 8;

  f32x4 acc[MT][2] = {};

  const int laneoff = (lane & 15) * 256 + (lane >> 4) * 8;  // DMA src offset in chunk
  const int fo = lane * 8;                                   // frag offset (u16)

  bf16x8 nbh0, nbh1, nbl0, nbl1;

  for (int pass = 0; pass < PASSES; ++pass) {
    const int kbase = pass * (KS * 32);
    if (pass > 0) __syncthreads();   // all waves done reading ABUF before restage
    // ---- stage A chunks for this pass: c = ks*(2*MT) + part*MT + mt ----
#pragma unroll
    for (int j = 0; j < 8; ++j) {
      int c = w * 8 + j;
      int ks = c / (2 * MT);
      int rem = c % (2 * MT);
      int part = rem / MT;
      int mt = rem % MT;
      const u16* src = Aab + part * (R * 256) + mt * 4096 + kbase + ks * 32 + laneoff;
      g2l16(src, ABUF + c * 512);
    }
    // prefetch B for first kstep of this pass (register-destined, no LDS dep)
    {
      const int k0 = kbase;
      nbh0 = *(const bf16x8*)(Bp + k0);
      nbh1 = *(const bf16x8*)(Bp + 4096 + k0);
      nbl0 = *(const bf16x8*)(Bp + 65536 + k0);
      nbl1 = *(const bf16x8*)(Bp + 69632 + k0);
    }
    __syncthreads();   // drain A-DMA

    // ---- K-loop of this pass: NO barriers ----
#pragma unroll
    for (int ks = 0; ks < KS; ++ks) {
      bf16x8 bh0 = nbh0, bh1 = nbh1, bl0 = nbl0, bl1 = nbl1;
      if (ks + 1 < KS) {
        const int k0 = kbase + (ks + 1) * 32;
        nbh0 = *(const bf16x8*)(Bp + k0);
        nbh1 = *(const bf16x8*)(Bp + 4096 + k0);
        nbl0 = *(const bf16x8*)(Bp + 65536 + k0);
        nbl1 = *(const bf16x8*)(Bp + 69632 + k0);
      }
#pragma unroll
      for (int mt = 0; mt < MT; ++mt) {
        bf16x8 ah = *(const bf16x8*)(ABUF + (ks * 2 * MT + mt) * 512 + fo);
        bf16x8 al = *(const bf16x8*)(ABUF + (ks * 2 * MT + MT + mt) * 512 + fo);
        acc[mt][0] = __builtin_amdgcn_mfma_f32_16x16x32_bf16(al, bh0, acc[mt][0], 0, 0, 0);
        acc[mt][0] = __builtin_amdgcn_mfma_f32_16x16x32_bf16(ah, bl0, acc[mt][0], 0, 0, 0);
        acc[mt][0] = __builtin_amdgcn_mfma_f32_16x16x32_bf16(ah, bh0, acc[mt][0], 0, 0, 0);
        acc[mt][1] = __builtin_amdgcn_mfma_f32_16x16x32_bf16(al, bh1, acc[mt][1], 0, 0, 0);
        acc[mt][1] = __builtin_amdgcn_mfma_f32_16x16x32_bf16(ah, bl1, acc[mt][1], 0, 0, 0);
        acc[mt][1] = __builtin_amdgcn_mfma_f32_16x16x32_bf16(ah, bh1, acc[mt][1], 0, 0, 0);
      }
    }
  }

  // ---- dynamic routing (3 iterations) on register-resident P ----
  const float invR = 1.0f / R;
  float v[2];

  for (int iter = 0; iter < 3; ++iter) {
    // s[e] = sum_b probs[b] * P[b,e] : in-lane over (mt,r), butterfly over q
    float s[2];
#pragma unroll
    for (int ct = 0; ct < 2; ++ct) {
      float t = 0.f;
#pragma unroll
      for (int mt = 0; mt < MT; ++mt) {
        float4 p4;
        if (iter == 0) { p4.x = invR; p4.y = invR; p4.z = invR; p4.w = invR; }
        else           { p4 = *(const float4*)&probs[mt * 16 + q * 4]; }
        t += p4.x * acc[mt][ct][0];
        t += p4.y * acc[mt][ct][1];
        t += p4.z * acc[mt][ct][2];
        t += p4.w * acc[mt][ct][3];
      }
      t += __shfl_xor(t, 16);
      t += __shfl_xor(t, 32);
      s[ct] = t;
    }
    // squash: per-wave 32-col partial via li-butterfly, cross-wave via LDS
    float ss = s[0] * s[0] + s[1] * s[1];
    ss += __shfl_xor(ss, 1);
    ss += __shfl_xor(ss, 2);
    ss += __shfl_xor(ss, 4);
    ss += __shfl_xor(ss, 8);
    if (lane == 0) sqpart[w] = ss;
    __syncthreads();
    float sq = sqpart[0] + sqpart[1] + sqpart[2] + sqpart[3] +
               sqpart[4] + sqpart[5] + sqpart[6] + sqpart[7];
    float scale = (sq > 0.f) ? sq / ((1.0f + sq) * sqrtf(sq)) : 0.f;
    v[0] = s[0] * scale;
    v[1] = s[1] * scale;

    if (iter < 2) {
      // logits[b] += sum_e P[b,e]*v[e] : in-lane over ct, butterfly over li, LDS over w
#pragma unroll
      for (int mt = 0; mt < MT; ++mt) {
        float t0, t1, t2, t3;
        {
          float t = acc[mt][0][0] * v[0] + acc[mt][1][0] * v[1];
          t += __shfl_xor(t, 1); t += __shfl_xor(t, 2);
          t += __shfl_xor(t, 4); t += __shfl_xor(t, 8);
          t0 = t;
        }
        {
          float t = acc[mt][0][1] * v[0] + acc[mt][1][1] * v[1];
          t += __shfl_xor(t, 1); t += __shfl_xor(t, 2);
          t += __shfl_xor(t, 4); t += __shfl_xor(t, 8);
          t1 = t;
        }
        {
          float t = acc[mt][0][2] * v[0] + acc[mt][1][2] * v[1];
          t += __shfl_xor(t, 1); t += __shfl_xor(t, 2);
          t += __shfl_xor(t, 4); t += __shfl_xor(t, 8);
          t2 = t;
        }
        {
          float t = acc[mt][0][3] * v[0] + acc[mt][1][3] * v[1];
          t += __shfl_xor(t, 1); t += __shfl_xor(t, 2);
          t += __shfl_xor(t, 4); t += __shfl_xor(t, 8);
          t3 = t;
        }
        if (li == 0)
          *(float4*)&wlog[w][mt * 16 + q * 4] = make_float4(t0, t1, t2, t3);
      }
      __syncthreads();
      if (tid < R) {
        float l = (iter == 0 ? 0.f : logits[tid]);
        l += wlog[0][tid] + wlog[1][tid] + wlog[2][tid] + wlog[3][tid] +
             wlog[4][tid] + wlog[5][tid] + wlog[6][tid] + wlog[7][tid];
        logits[tid] = l;
      }
      __syncthreads();
      if (w == 0) {  // softmax over R logits, wave 0
        float l0 = logits[lane];
        float l1 = (R == 128) ? logits[lane + 64] : -3.0e38f;
        float m = fmaxf(l0, l1);
#pragma unroll
        for (int d2 = 1; d2 < 64; d2 <<= 1) m = fmaxf(m, __shfl_xor(m, d2));
        float e0 = expf(l0 - m);
        float e1 = (R == 128) ? expf(l1 - m) : 0.f;
        float zz = e0 + e1;
#pragma unroll
        for (int d2 = 1; d2 < 64; d2 <<= 1) zz += __shfl_xor(zz, d2);
        float inv = 1.0f / zz;
        probs[lane] = e0 * inv;
        if (R == 128) probs[lane + 64] = e1 * inv;
      }
      __syncthreads();
    }
  }

  // ---- epilogue. stage1 -> o1[a][2][KN][256] split; stage2 -> fp32 out[kk][a][e] ----
  if (q == 0) {
    if (stage == 1) {
      size_t ob = (size_t)a * 2 * KN * 256 + (size_t)kk * 256;
#pragma unroll
      for (int ct = 0; ct < 2; ++ct) {
        int e = w * 32 + ct * 16 + li;
        u32 hb = bf16_rne(v[ct]);
        u32 lb = bf16_rne(v[ct] - bf16_val(hb));
        o1[ob + e] = (u16)hb;
        o1[ob + (size_t)KN * 256 + e] = (u16)lb;
      }
    } else {
      size_t ob = ((size_t)kk * 64 + a) * 256;
#pragma unroll
      for (int ct = 0; ct < 2; ++ct) {
        int e = w * 32 + ct * 16 + li;
        outp[ob + e] = v[ct];
      }
    }
  }
}

extern "C" void kernel_launch(void* const* d_in, const int* in_sizes, int n_in,
                              void* d_out, int out_size, void* d_ws, size_t ws_size,
                              hipStream_t stream) {
  const float* x  = (const float*)d_in[0];   // [64][128][256]
  const float* w1 = (const float*)d_in[1];   // [64][256][256]
  const float* wc = (const float*)d_in[2];   // [32][256][256]
  float* out = (float*)d_out;                // [32][64][256]

  char* ws = (char*)d_ws;
  u16* x2  = (u16*)(ws);                     // [64][2][128][256]  16 MB
  u16* w12 = (u16*)(ws + (16u << 20));       // [64][2][256][256]  16 MB
  u16* wc2 = (u16*)(ws + (32u << 20));       // [32][2][256][256]   8 MB
  u16* o1  = (u16*)(ws + (40u << 20));       // [64][2][64][256]    4 MB

  // x: 2,097,152 elems = 524,288 float4s; per-a chunk = 32768 elems (8192 f4)
  split_pairs<<<2048, 256, 0, stream>>>(x, x2, 524288, 8192);
  split_transpose256<<<dim3(8, 8, 64), dim3(32, 8), 0, stream>>>(w1, w12);
  split_transpose256<<<dim3(8, 8, 32), dim3(32, 8), 0, stream>>>(wc, wc2);
  caps_route<128><<<64 * 64, 512, 0, stream>>>(x2, w12, o1, nullptr, 64, 1);
  caps_route<64><<<32 * 64, 512, 0, stream>>>(o1, wc2, nullptr, out, 32, 2);
}